// Round 4
// baseline (436.157 us; speedup 1.0000x reference)
//
#include <hip/hip_runtime.h>
#include <hip/hip_bf16.h>
#include <stdint.h>

#define BATCH   4096
#define IN_DIM  1024
#define OUT_DIM 1024
#define GRID_G  8
#define NF      17               // 1 (silu) + 8 cos + 8 sin
#define KDIM    (IN_DIM * NF)    // 17408
#define SPLITK  4
#define KCHUNK  (KDIM / SPLITK)  // 4352 (136 k-steps of 32)

typedef __bf16 bf16x8 __attribute__((ext_vector_type(8)));
typedef float  f32x4  __attribute__((ext_vector_type(4)));

// ---------------------------------------------------------------------------
// Kernel 1: features F[b, k], k = f*IN_DIM + i
//   f=0: silu(x); f=1..8: cos(f*x); f=9..16: sin((f-8)*x)
// One thread per (b, 8 consecutive i). All stores are 16 B bf16x8.
// ---------------------------------------------------------------------------
__global__ void build_features(const float* __restrict__ x, __bf16* __restrict__ A) {
    int t  = blockIdx.x * blockDim.x + threadIdx.x;   // over BATCH*IN_DIM/8
    int b  = t >> 7;                                  // 128 groups of 8 per row
    int i0 = (t & 127) * 8;
    const float4* xp = (const float4*)(x + (size_t)b * IN_DIM + i0);
    float4 x0 = xp[0], x1 = xp[1];
    float xv[8] = {x0.x, x0.y, x0.z, x0.w, x1.x, x1.y, x1.z, x1.w};

    float c1[8], s1[8], ck[8], sk[8];
    bf16x8 v;
    __bf16* base = A + (size_t)b * KDIM + i0;

#pragma unroll
    for (int j = 0; j < 8; ++j) {
        float sil = xv[j] / (1.f + __expf(-xv[j]));
        v[j] = (__bf16)sil;
        __sincosf(xv[j], &s1[j], &c1[j]);
        ck[j] = c1[j]; sk[j] = s1[j];
    }
    *(bf16x8*)base = v;

#pragma unroll
    for (int g = 1; g <= GRID_G; ++g) {
        bf16x8 vc, vs;
#pragma unroll
        for (int j = 0; j < 8; ++j) {
            vc[j] = (__bf16)ck[j];
            vs[j] = (__bf16)sk[j];
            float cn = ck[j] * c1[j] - sk[j] * s1[j];
            float sn = sk[j] * c1[j] + ck[j] * s1[j];
            ck[j] = cn; sk[j] = sn;
        }
        *(bf16x8*)(base + (size_t)g * IN_DIM)            = vc;
        *(bf16x8*)(base + (size_t)(GRID_G + g) * IN_DIM) = vs;
    }
}

// ---------------------------------------------------------------------------
// Kernel 2: folded weights W[o, k], k = f*IN_DIM + i  (matches feature layout)
// ---------------------------------------------------------------------------
__global__ void fold_weights(const float* __restrict__ sb, const float* __restrict__ ss,
                             const float* __restrict__ coeff, __bf16* __restrict__ W) {
    int t  = blockIdx.x * blockDim.x + threadIdx.x;   // over OUT_DIM*IN_DIM/8
    int o  = t >> 7;
    int i0 = (t & 127) * 8;
    size_t oi = (size_t)o * IN_DIM + i0;

    float s[8];
    {
        const float4* sp = (const float4*)(ss + oi);
        float4 s0 = sp[0], s1 = sp[1];
        s[0]=s0.x; s[1]=s0.y; s[2]=s0.z; s[3]=s0.w;
        s[4]=s1.x; s[5]=s1.y; s[6]=s1.z; s[7]=s1.w;
    }
    __bf16* wb = W + (size_t)o * KDIM + i0;
    {
        const float4* bp = (const float4*)(sb + oi);
        float4 b0 = bp[0], b1 = bp[1];
        float bv[8] = {b0.x, b0.y, b0.z, b0.w, b1.x, b1.y, b1.z, b1.w};
        bf16x8 v;
#pragma unroll
        for (int j = 0; j < 8; ++j) v[j] = (__bf16)bv[j];
        *(bf16x8*)wb = v;
    }

#pragma unroll
    for (int p = 0; p < 2; ++p) {
        const float* cp = coeff + ((size_t)p * OUT_DIM * IN_DIM + oi) * GRID_G;
        float c[8][8];                     // [j][g]
#pragma unroll
        for (int j = 0; j < 8; ++j) {
            const float4* cj = (const float4*)(cp + (size_t)j * GRID_G);
            float4 a0 = cj[0], a1 = cj[1];
            c[j][0]=a0.x; c[j][1]=a0.y; c[j][2]=a0.z; c[j][3]=a0.w;
            c[j][4]=a1.x; c[j][5]=a1.y; c[j][6]=a1.z; c[j][7]=a1.w;
        }
#pragma unroll
        for (int g = 0; g < GRID_G; ++g) {
            bf16x8 v;
#pragma unroll
            for (int j = 0; j < 8; ++j) v[j] = (__bf16)(s[j] * c[j][g]);
            *(bf16x8*)(wb + (size_t)(1 + p * GRID_G + g) * IN_DIM) = v;
        }
    }
}

// ---------------------------------------------------------------------------
// Kernel 3: split-K GEMM, 128x128 tile, BK=32, 4 waves 2x2.
// LDS XOR-swizzle: global chunk c of row r stored at LDS chunk c ^ ((r>>1)&3)
// so fragment reads start on banks {0,4,...,28} (2-way wave64 aliasing only,
// which is free per m136). The swizzle is applied on the staging GLOBAL
// address (global_load_lds dest is fixed at base + lane*16B); it permutes
// 16B chunks within the same 64B segment -> coalescing unchanged.
// Epilogue: HW f32 atomic add into zeroed d_out (single path, graph-proven).
// Grid 32x8x4 = 1024 blocks -> 4 blocks/CU.
// ---------------------------------------------------------------------------
__global__ __launch_bounds__(256) void gemm_bt(const __bf16* __restrict__ A,
                                               const __bf16* __restrict__ B,
                                               float* __restrict__ C) {
    __shared__ __align__(16) __bf16 As[128 * 32];
    __shared__ __align__(16) __bf16 Bs[128 * 32];
    const int tid = threadIdx.x;
    const int w   = tid >> 6;      // wave 0..3
    const int l   = tid & 63;      // lane
    const int bm  = blockIdx.x;    // M/128 = 32
    const int bn  = blockIdx.y;    // N/128 = 8
    const int kz  = blockIdx.z;    // split-K chunk
    const int wm  = w & 1;
    const int wn  = w >> 1;

    f32x4 acc[4][4] = {};

    // staging: lane l fills LDS row w*16 + (l>>2), LDS chunk (l&3);
    // source global chunk = (l&3) ^ (row bits 1..2) = (l&3) ^ ((l>>3)&3)
    const int lr  = l >> 2;
    const int lcs = ((l & 3) ^ ((l >> 3) & 3)) * 8;
    const int kbeg = kz * KCHUNK;
    const __bf16* Ag = A + (size_t)(bm * 128) * KDIM;
    const __bf16* Bg = B + (size_t)(bn * 128) * KDIM;
    const int rowA = w * 16 + lr;
    const __bf16* a0 = Ag + (size_t)rowA * KDIM + kbeg + lcs;
    const __bf16* a1 = Ag + (size_t)(rowA + 64) * KDIM + kbeg + lcs;
    const __bf16* b0 = Bg + (size_t)rowA * KDIM + kbeg + lcs;
    const __bf16* b1 = Bg + (size_t)(rowA + 64) * KDIM + kbeg + lcs;

    // fragment-read LDS offsets (loop-invariant): wanted global chunk l>>4 of
    // row (...)*16+lm -> stored at chunk (l>>4) ^ ((lm>>1)&3)
    const int lm  = l & 15;
    const int csw = ((l >> 4) ^ ((lm >> 1) & 3)) * 8;
    int aoff[4], boff[4];
#pragma unroll
    for (int i = 0; i < 4; ++i) {
        aoff[i] = (wm * 64 + i * 16 + lm) * 32 + csw;
        boff[i] = (wn * 64 + i * 16 + lm) * 32 + csw;
    }

    for (int ks = 0; ks < KCHUNK / 32; ++ks) {
        __builtin_amdgcn_global_load_lds((const uint32_t*)a0, (uint32_t*)(As + w * 512),        16, 0, 0);
        __builtin_amdgcn_global_load_lds((const uint32_t*)a1, (uint32_t*)(As + 2048 + w * 512), 16, 0, 0);
        __builtin_amdgcn_global_load_lds((const uint32_t*)b0, (uint32_t*)(Bs + w * 512),        16, 0, 0);
        __builtin_amdgcn_global_load_lds((const uint32_t*)b1, (uint32_t*)(Bs + 2048 + w * 512), 16, 0, 0);
        a0 += 32; a1 += 32; b0 += 32; b1 += 32;
        __syncthreads();

        bf16x8 af[4], bfr[4];
#pragma unroll
        for (int i = 0; i < 4; ++i) af[i]  = *(const bf16x8*)(As + aoff[i]);
#pragma unroll
        for (int j = 0; j < 4; ++j) bfr[j] = *(const bf16x8*)(Bs + boff[j]);
#pragma unroll
        for (int i = 0; i < 4; ++i)
#pragma unroll
            for (int j = 0; j < 4; ++j)
                acc[i][j] = __builtin_amdgcn_mfma_f32_16x16x32_bf16(af[i], bfr[j], acc[i][j], 0, 0, 0);
        __syncthreads();
    }

    // epilogue: C/D layout col = lane&15, row = (lane>>4)*4 + reg
    const int row0 = bm * 128 + wm * 64 + ((l >> 4) * 4);
    const int col0 = bn * 128 + wn * 64 + (l & 15);
#pragma unroll
    for (int i = 0; i < 4; ++i)
#pragma unroll
        for (int j = 0; j < 4; ++j)
#pragma unroll
            for (int r = 0; r < 4; ++r)
                unsafeAtomicAdd(&C[(size_t)(row0 + i * 16 + r) * OUT_DIM + col0 + j * 16],
                                acc[i][j][r]);
}

// ---------------------------------------------------------------------------
extern "C" void kernel_launch(void* const* d_in, const int* in_sizes, int n_in,
                              void* d_out, int out_size, void* d_ws, size_t ws_size,
                              hipStream_t stream) {
    const float* x     = (const float*)d_in[0];   // (B, I)
    const float* sb    = (const float*)d_in[1];   // (O, I)
    const float* ss    = (const float*)d_in[2];   // (O, I)
    const float* coeff = (const float*)d_in[3];   // (2, O, I, G)
    float* out = (float*)d_out;                   // (B, O)

    __bf16* A = (__bf16*)d_ws;                        // BATCH * KDIM bf16 = 142.6 MB
    __bf16* W = A + (size_t)BATCH * KDIM;             // OUT_DIM * KDIM bf16 = 35.7 MB

    hipLaunchKernelGGL(build_features, dim3((BATCH * IN_DIM / 8) / 256), dim3(256), 0, stream, x, A);
    hipLaunchKernelGGL(fold_weights, dim3((OUT_DIM * IN_DIM / 8) / 256), dim3(256), 0, stream,
                       sb, ss, coeff, W);
    hipMemsetAsync(out, 0, (size_t)BATCH * OUT_DIM * sizeof(float), stream);
    hipLaunchKernelGGL(gemm_bt, dim3(BATCH / 128, OUT_DIM / 128, SPLITK), dim3(256), 0, stream,
                       A, W, out);
}

// Round 5
// 367.879 us; speedup vs baseline: 1.1856x; 1.1856x over previous
//
#include <hip/hip_runtime.h>
#include <hip/hip_bf16.h>
#include <stdint.h>

#define BATCH   4096
#define IN_DIM  1024
#define OUT_DIM 1024
#define GRID_G  8
#define NF      17               // 1 (silu) + 8 cos + 8 sin
#define KDIM    (IN_DIM * NF)    // 17408
#define SPLITK  4
#define KCHUNK  (KDIM / SPLITK)  // 4352 (68 k-steps of 64)

typedef __bf16 bf16x8 __attribute__((ext_vector_type(8)));
typedef float  f32x4  __attribute__((ext_vector_type(4)));

// ---------------------------------------------------------------------------
// Prep (merged): blocks [0, 2048) build features A[b,k]; blocks [2048, 2560)
// fold weights W[o,k]. k = f*IN_DIM + i; f=0 silu/base, f=1..8 cos, f=9..16 sin.
// One thread handles 8 consecutive i; all stores are 16 B bf16x8.
// ---------------------------------------------------------------------------
__global__ void prep(const float* __restrict__ x, const float* __restrict__ sb,
                     const float* __restrict__ ss, const float* __restrict__ coeff,
                     __bf16* __restrict__ A, __bf16* __restrict__ W) {
    if (blockIdx.x < 2048) {
        int t  = blockIdx.x * blockDim.x + threadIdx.x;   // over BATCH*IN_DIM/8
        int b  = t >> 7;
        int i0 = (t & 127) * 8;
        const float4* xp = (const float4*)(x + (size_t)b * IN_DIM + i0);
        float4 x0 = xp[0], x1 = xp[1];
        float xv[8] = {x0.x, x0.y, x0.z, x0.w, x1.x, x1.y, x1.z, x1.w};

        float c1[8], s1[8], ck[8], sk[8];
        bf16x8 v;
        __bf16* base = A + (size_t)b * KDIM + i0;
#pragma unroll
        for (int j = 0; j < 8; ++j) {
            float sil = xv[j] / (1.f + __expf(-xv[j]));
            v[j] = (__bf16)sil;
            __sincosf(xv[j], &s1[j], &c1[j]);
            ck[j] = c1[j]; sk[j] = s1[j];
        }
        *(bf16x8*)base = v;
#pragma unroll
        for (int g = 1; g <= GRID_G; ++g) {
            bf16x8 vc, vs;
#pragma unroll
            for (int j = 0; j < 8; ++j) {
                vc[j] = (__bf16)ck[j];
                vs[j] = (__bf16)sk[j];
                float cn = ck[j] * c1[j] - sk[j] * s1[j];
                float sn = sk[j] * c1[j] + ck[j] * s1[j];
                ck[j] = cn; sk[j] = sn;
            }
            *(bf16x8*)(base + (size_t)g * IN_DIM)            = vc;
            *(bf16x8*)(base + (size_t)(GRID_G + g) * IN_DIM) = vs;
        }
    } else {
        int t  = (blockIdx.x - 2048) * blockDim.x + threadIdx.x; // over OUT_DIM*IN_DIM/8
        int o  = t >> 7;
        int i0 = (t & 127) * 8;
        size_t oi = (size_t)o * IN_DIM + i0;

        float s[8];
        {
            const float4* sp = (const float4*)(ss + oi);
            float4 s0 = sp[0], s1 = sp[1];
            s[0]=s0.x; s[1]=s0.y; s[2]=s0.z; s[3]=s0.w;
            s[4]=s1.x; s[5]=s1.y; s[6]=s1.z; s[7]=s1.w;
        }
        __bf16* wb = W + (size_t)o * KDIM + i0;
        {
            const float4* bp = (const float4*)(sb + oi);
            float4 b0 = bp[0], b1 = bp[1];
            float bv[8] = {b0.x, b0.y, b0.z, b0.w, b1.x, b1.y, b1.z, b1.w};
            bf16x8 v;
#pragma unroll
            for (int j = 0; j < 8; ++j) v[j] = (__bf16)bv[j];
            *(bf16x8*)wb = v;
        }
#pragma unroll
        for (int p = 0; p < 2; ++p) {
            const float* cp = coeff + ((size_t)p * OUT_DIM * IN_DIM + oi) * GRID_G;
            float c[8][8];                     // [j][g]
#pragma unroll
            for (int j = 0; j < 8; ++j) {
                const float4* cj = (const float4*)(cp + (size_t)j * GRID_G);
                float4 a0 = cj[0], a1 = cj[1];
                c[j][0]=a0.x; c[j][1]=a0.y; c[j][2]=a0.z; c[j][3]=a0.w;
                c[j][4]=a1.x; c[j][5]=a1.y; c[j][6]=a1.z; c[j][7]=a1.w;
            }
#pragma unroll
            for (int g = 0; g < GRID_G; ++g) {
                bf16x8 v;
#pragma unroll
                for (int j = 0; j < 8; ++j) v[j] = (__bf16)(s[j] * c[j][g]);
                *(bf16x8*)(wb + (size_t)(1 + p * GRID_G + g) * IN_DIM) = v;
            }
        }
    }
}

// ---------------------------------------------------------------------------
// GEMM: split-K x4, 128x128 tile, BK=64 (68 iterations -> half the barrier
// drains of BK=32), 4 waves 2x2, 32 KB LDS (4 blocks/CU within 160 KB).
// __launch_bounds__(256,4): pin combined VGPR+AGPR <= 128 so 4 blocks/CU
// stay resident (R4 lesson: 92 VGPR + 64 AGPR -> 3 blocks/CU, -15%).
// LDS XOR-swizzle: global 16B-chunk c of row r stored at chunk c ^ (r&7);
// fragment reads then start on distinct bank quads (2-way aliasing = free).
// Applied on the staging GLOBAL address; permutes chunks within one 128 B
// row segment -> coalescing unchanged.
// ---------------------------------------------------------------------------
__global__ __launch_bounds__(256, 4) void gemm_bt(const __bf16* __restrict__ A,
                                                  const __bf16* __restrict__ B,
                                                  float* __restrict__ C) {
    __shared__ __align__(16) __bf16 As[128 * 64];   // 16 KB
    __shared__ __align__(16) __bf16 Bs[128 * 64];   // 16 KB
    const int tid = threadIdx.x;
    const int w   = tid >> 6;      // wave 0..3
    const int l   = tid & 63;      // lane
    const int bm  = blockIdx.x;    // M/128 = 32
    const int bn  = blockIdx.y;    // N/128 = 8
    const int kz  = blockIdx.z;    // split-K chunk
    const int wm  = w & 1;
    const int wn  = w >> 1;

    f32x4 acc[4][4] = {};

    // staging: per instr j (0..3): rows w*32 + j*8 .. +8; lane -> row += l>>3,
    // LDS chunk (l&7); source global chunk = (l&7) ^ ((l>>3)&7)
    const int srow   = l >> 3;                    // 0..7
    const int schunk = ((l & 7) ^ srow) * 8;      // element offset within 64
    const int kbeg   = kz * KCHUNK;
    const __bf16* Ag = A + (size_t)(bm * 128 + w * 32 + srow) * KDIM + kbeg + schunk;
    const __bf16* Bg = B + (size_t)(bn * 128 + w * 32 + srow) * KDIM + kbeg + schunk;

    const int lm = l & 15;
    const int kq = l >> 4;        // 0..3

    for (int ks = 0; ks < KCHUNK / 64; ++ks) {
#pragma unroll
        for (int j = 0; j < 4; ++j) {
            __builtin_amdgcn_global_load_lds(
                (const uint32_t*)(Ag + (size_t)(j * 8) * KDIM),
                (uint32_t*)(As + (w * 32 + j * 8) * 64), 16, 0, 0);
            __builtin_amdgcn_global_load_lds(
                (const uint32_t*)(Bg + (size_t)(j * 8) * KDIM),
                (uint32_t*)(Bs + (w * 32 + j * 8) * 64), 16, 0, 0);
        }
        Ag += 64; Bg += 64;
        __syncthreads();

#pragma unroll
        for (int h = 0; h < 2; ++h) {
            const int sc = ((h * 4 + kq) ^ (lm & 7)) * 8;   // swizzled chunk offset
            bf16x8 af[4], bfr[4];
#pragma unroll
            for (int i = 0; i < 4; ++i)
                af[i]  = *(const bf16x8*)(As + (wm * 64 + i * 16 + lm) * 64 + sc);
#pragma unroll
            for (int j = 0; j < 4; ++j)
                bfr[j] = *(const bf16x8*)(Bs + (wn * 64 + j * 16 + lm) * 64 + sc);
#pragma unroll
            for (int i = 0; i < 4; ++i)
#pragma unroll
                for (int j = 0; j < 4; ++j)
                    acc[i][j] = __builtin_amdgcn_mfma_f32_16x16x32_bf16(af[i], bfr[j], acc[i][j], 0, 0, 0);
        }
        __syncthreads();
    }

    // epilogue: C/D layout col = lane&15, row = (lane>>4)*4 + reg
    const int row0 = bm * 128 + wm * 64 + ((l >> 4) * 4);
    const int col0 = bn * 128 + wn * 64 + (l & 15);
#pragma unroll
    for (int i = 0; i < 4; ++i)
#pragma unroll
        for (int j = 0; j < 4; ++j)
#pragma unroll
            for (int r = 0; r < 4; ++r)
                unsafeAtomicAdd(&C[(size_t)(row0 + i * 16 + r) * OUT_DIM + col0 + j * 16],
                                acc[i][j][r]);
}

// ---------------------------------------------------------------------------
extern "C" void kernel_launch(void* const* d_in, const int* in_sizes, int n_in,
                              void* d_out, int out_size, void* d_ws, size_t ws_size,
                              hipStream_t stream) {
    const float* x     = (const float*)d_in[0];   // (B, I)
    const float* sb    = (const float*)d_in[1];   // (O, I)
    const float* ss    = (const float*)d_in[2];   // (O, I)
    const float* coeff = (const float*)d_in[3];   // (2, O, I, G)
    float* out = (float*)d_out;                   // (B, O)

    __bf16* A = (__bf16*)d_ws;                        // BATCH * KDIM bf16 = 142.6 MB
    __bf16* W = A + (size_t)BATCH * KDIM;             // OUT_DIM * KDIM bf16 = 35.7 MB

    hipLaunchKernelGGL(prep, dim3(2048 + 512), dim3(256), 0, stream, x, sb, ss, coeff, A, W);
    hipMemsetAsync(out, 0, (size_t)BATCH * OUT_DIM * sizeof(float), stream);
    hipLaunchKernelGGL(gemm_bt, dim3(BATCH / 128, OUT_DIM / 128, SPLITK), dim3(256), 0, stream,
                       A, W, out);
}

// Round 6
// 299.255 us; speedup vs baseline: 1.4575x; 1.2293x over previous
//
#include <hip/hip_runtime.h>
#include <hip/hip_bf16.h>
#include <stdint.h>

#define BATCH   4096
#define IN_DIM  1024
#define OUT_DIM 1024
#define GRID_G  8
#define K8      16384            // spline K: 16 planes (8 cos + 8 sin) * 1024
#define KB      1024             // base K (silu plane)
#define SPLIT8  4                // spline split-K: 32 iters of BK=128 each
#define SPLITB  2                // base split-K: 8 iters of BK=64 each
#define WSCALE  256.0f           // spline weights scaled into e4m3 range

typedef __bf16 bf16x8 __attribute__((ext_vector_type(8)));
typedef float  f32x4  __attribute__((ext_vector_type(4)));
typedef long   fp8x8;            // 8 fp8 bytes in 2 VGPRs

// pack 8 floats -> 8 fp8 e4m3 bytes (HW cvt), little-endian k-order
__device__ inline void store_fp8x8(void* p, const float v[8]) {
    int lo = 0, hi = 0;
    lo = __builtin_amdgcn_cvt_pk_fp8_f32(v[0], v[1], lo, false);
    lo = __builtin_amdgcn_cvt_pk_fp8_f32(v[2], v[3], lo, true);
    hi = __builtin_amdgcn_cvt_pk_fp8_f32(v[4], v[5], hi, false);
    hi = __builtin_amdgcn_cvt_pk_fp8_f32(v[6], v[7], hi, true);
    *(int2*)p = make_int2(lo, hi);
}

// ---------------------------------------------------------------------------
// Prep (merged): blocks [0,2048) build features; [2048,2560) fold weights.
// Spline planes (fp8): A8[b, p*1024+i], p=0..7 cos(g=p+1), p=8..15 sin(g=p-7).
// Base plane (bf16):   Ab[b,i] = silu(x);  Wb[o,i] = scale_base.
// W8[o, p*1024+i] = ss*coeff*WSCALE (fp8).
// ---------------------------------------------------------------------------
__global__ void prep(const float* __restrict__ x, const float* __restrict__ sb,
                     const float* __restrict__ ss, const float* __restrict__ coeff,
                     uint8_t* __restrict__ A8, uint8_t* __restrict__ W8,
                     __bf16* __restrict__ Ab, __bf16* __restrict__ Wb) {
    if (blockIdx.x < 2048) {
        int t  = blockIdx.x * blockDim.x + threadIdx.x;   // over BATCH*IN_DIM/8
        int b  = t >> 7;
        int i0 = (t & 127) * 8;
        const float4* xp = (const float4*)(x + (size_t)b * IN_DIM + i0);
        float4 x0 = xp[0], x1 = xp[1];
        float xv[8] = {x0.x, x0.y, x0.z, x0.w, x1.x, x1.y, x1.z, x1.w};

        float c1[8], s1[8], ck[8], sk[8];
        bf16x8 v;
#pragma unroll
        for (int j = 0; j < 8; ++j) {
            float sil = xv[j] / (1.f + __expf(-xv[j]));
            v[j] = (__bf16)sil;
            __sincosf(xv[j], &s1[j], &c1[j]);
            ck[j] = c1[j]; sk[j] = s1[j];
        }
        *(bf16x8*)(Ab + (size_t)b * IN_DIM + i0) = v;

        uint8_t* a8 = A8 + (size_t)b * K8 + i0;
#pragma unroll
        for (int g = 1; g <= GRID_G; ++g) {
            float vc[8], vs[8];
#pragma unroll
            for (int j = 0; j < 8; ++j) {
                vc[j] = ck[j];
                vs[j] = sk[j];
                float cn = ck[j] * c1[j] - sk[j] * s1[j];
                float sn = sk[j] * c1[j] + ck[j] * s1[j];
                ck[j] = cn; sk[j] = sn;
            }
            store_fp8x8(a8 + (size_t)(g - 1) * IN_DIM, vc);
            store_fp8x8(a8 + (size_t)(GRID_G + g - 1) * IN_DIM, vs);
        }
    } else {
        int t  = (blockIdx.x - 2048) * blockDim.x + threadIdx.x; // over OUT_DIM*IN_DIM/8
        int o  = t >> 7;
        int i0 = (t & 127) * 8;
        size_t oi = (size_t)o * IN_DIM + i0;

        float s[8];
        {
            const float4* sp = (const float4*)(ss + oi);
            float4 s0 = sp[0], s1 = sp[1];
            s[0]=s0.x; s[1]=s0.y; s[2]=s0.z; s[3]=s0.w;
            s[4]=s1.x; s[5]=s1.y; s[6]=s1.z; s[7]=s1.w;
        }
        {
            const float4* bp = (const float4*)(sb + oi);
            float4 b0 = bp[0], b1 = bp[1];
            float bv[8] = {b0.x, b0.y, b0.z, b0.w, b1.x, b1.y, b1.z, b1.w};
            bf16x8 v;
#pragma unroll
            for (int j = 0; j < 8; ++j) v[j] = (__bf16)bv[j];
            *(bf16x8*)(Wb + oi) = v;
        }
        uint8_t* w8 = W8 + (size_t)o * K8 + i0;
#pragma unroll
        for (int p = 0; p < 2; ++p) {
            const float* cp = coeff + ((size_t)p * OUT_DIM * IN_DIM + oi) * GRID_G;
            float c[8][8];                     // [j][g]
#pragma unroll
            for (int j = 0; j < 8; ++j) {
                const float4* cj = (const float4*)(cp + (size_t)j * GRID_G);
                float4 a0 = cj[0], a1 = cj[1];
                c[j][0]=a0.x; c[j][1]=a0.y; c[j][2]=a0.z; c[j][3]=a0.w;
                c[j][4]=a1.x; c[j][5]=a1.y; c[j][6]=a1.z; c[j][7]=a1.w;
            }
#pragma unroll
            for (int g = 0; g < GRID_G; ++g) {
                float v[8];
#pragma unroll
                for (int j = 0; j < 8; ++j) v[j] = s[j] * c[j][g] * WSCALE;
                store_fp8x8(w8 + (size_t)(p * GRID_G + g) * IN_DIM, v);
            }
        }
    }
}

// ---------------------------------------------------------------------------
// Spline GEMM (fp8 e4m3): 128x128 tile, BK=128 bytes, split-K x4 -> 32 iters.
// 4 waves 2x2; 32 KB LDS; XOR chunk-swizzle (c ^ (r&7)) applied on the
// staging global address (16B chunks within a 128 B row) -> conflict-free.
// Epilogue scales by 1/WSCALE and atomically adds into C.
// ---------------------------------------------------------------------------
__global__ __launch_bounds__(256, 4) void gemm8(const uint8_t* __restrict__ A,
                                                const uint8_t* __restrict__ B,
                                                float* __restrict__ C) {
    __shared__ __align__(16) uint8_t As[128 * 128];   // 16 KB
    __shared__ __align__(16) uint8_t Bs[128 * 128];   // 16 KB
    const int tid = threadIdx.x;
    const int w   = tid >> 6;
    const int l   = tid & 63;
    const int bn  = blockIdx.x;    // N/128 = 8  (fastest: blocks share A-slice)
    const int bm  = blockIdx.y;    // M/128 = 32
    const int kz  = blockIdx.z;
    const int wm  = w & 1;
    const int wn  = w >> 1;

    f32x4 acc[4][4] = {};

    const int srow   = l >> 3;                  // 0..7
    const int schunk = ((l & 7) ^ srow) * 16;   // byte offset of 16B chunk
    const int kbeg   = kz * (K8 / SPLIT8);
    const uint8_t* Ag = A + (size_t)(bm * 128 + w * 32 + srow) * K8 + kbeg + schunk;
    const uint8_t* Bg = B + (size_t)(bn * 128 + w * 32 + srow) * K8 + kbeg + schunk;

    const int lm = l & 15;
    const int kq = l >> 4;        // 0..3
    const int kqh = kq >> 1, kql = (kq & 1) * 8;

    for (int ks = 0; ks < (K8 / SPLIT8) / 128; ++ks) {
#pragma unroll
        for (int j = 0; j < 4; ++j) {
            __builtin_amdgcn_global_load_lds(
                (const uint32_t*)(Ag + (size_t)(j * 8) * K8),
                (uint32_t*)(As + (w * 32 + j * 8) * 128), 16, 0, 0);
            __builtin_amdgcn_global_load_lds(
                (const uint32_t*)(Bg + (size_t)(j * 8) * K8),
                (uint32_t*)(Bs + (w * 32 + j * 8) * 128), 16, 0, 0);
        }
        Ag += 128; Bg += 128;
        __syncthreads();

#pragma unroll
        for (int s = 0; s < 4; ++s) {
            // lane wants bytes [s*32 + kq*8, +8) of row; chunk = s*2 + kq>>1
            const int c = s * 2 + kqh;
            fp8x8 af[4], bfr[4];
#pragma unroll
            for (int i = 0; i < 4; ++i) {
                int row = wm * 64 + i * 16 + lm;
                af[i] = *(const fp8x8*)(As + row * 128 + ((c ^ (row & 7)) << 4) + kql);
            }
#pragma unroll
            for (int j = 0; j < 4; ++j) {
                int row = wn * 64 + j * 16 + lm;
                bfr[j] = *(const fp8x8*)(Bs + row * 128 + ((c ^ (row & 7)) << 4) + kql);
            }
#pragma unroll
            for (int i = 0; i < 4; ++i)
#pragma unroll
                for (int j = 0; j < 4; ++j)
                    acc[i][j] = __builtin_amdgcn_mfma_f32_16x16x32_fp8_fp8(af[i], bfr[j], acc[i][j], 0, 0, 0);
        }
        __syncthreads();
    }

    const float inv = 1.0f / WSCALE;
    const int row0 = bm * 128 + wm * 64 + ((l >> 4) * 4);
    const int col0 = bn * 128 + wn * 64 + lm;
#pragma unroll
    for (int i = 0; i < 4; ++i)
#pragma unroll
        for (int j = 0; j < 4; ++j)
#pragma unroll
            for (int r = 0; r < 4; ++r)
                unsafeAtomicAdd(&C[(size_t)(row0 + i * 16 + r) * OUT_DIM + col0 + j * 16],
                                acc[i][j][r] * inv);
}

// ---------------------------------------------------------------------------
// Base GEMM (bf16, K=1024): 128x128 tile, BK=64, split-K x2 -> 8 iters.
// Same structure/swizzle as R5's proven kernel; stride = KB.
// ---------------------------------------------------------------------------
__global__ __launch_bounds__(256, 4) void gemmb(const __bf16* __restrict__ A,
                                                const __bf16* __restrict__ B,
                                                float* __restrict__ C) {
    __shared__ __align__(16) __bf16 As[128 * 64];   // 16 KB
    __shared__ __align__(16) __bf16 Bs[128 * 64];   // 16 KB
    const int tid = threadIdx.x;
    const int w   = tid >> 6;
    const int l   = tid & 63;
    const int bn  = blockIdx.x;
    const int bm  = blockIdx.y;
    const int kz  = blockIdx.z;
    const int wm  = w & 1;
    const int wn  = w >> 1;

    f32x4 acc[4][4] = {};

    const int srow   = l >> 3;
    const int schunk = ((l & 7) ^ srow) * 8;      // element offset within 64
    const int kbeg   = kz * (KB / SPLITB);
    const __bf16* Ag = A + (size_t)(bm * 128 + w * 32 + srow) * KB + kbeg + schunk;
    const __bf16* Bg = B + (size_t)(bn * 128 + w * 32 + srow) * KB + kbeg + schunk;

    const int lm = l & 15;
    const int kq = l >> 4;

    for (int ks = 0; ks < (KB / SPLITB) / 64; ++ks) {
#pragma unroll
        for (int j = 0; j < 4; ++j) {
            __builtin_amdgcn_global_load_lds(
                (const uint32_t*)(Ag + (size_t)(j * 8) * KB),
                (uint32_t*)(As + (w * 32 + j * 8) * 64), 16, 0, 0);
            __builtin_amdgcn_global_load_lds(
                (const uint32_t*)(Bg + (size_t)(j * 8) * KB),
                (uint32_t*)(Bs + (w * 32 + j * 8) * 64), 16, 0, 0);
        }
        Ag += 64; Bg += 64;
        __syncthreads();

#pragma unroll
        for (int h = 0; h < 2; ++h) {
            const int sc = ((h * 4 + kq) ^ (lm & 7)) * 8;
            bf16x8 af[4], bfr[4];
#pragma unroll
            for (int i = 0; i < 4; ++i)
                af[i]  = *(const bf16x8*)(As + (wm * 64 + i * 16 + lm) * 64 + sc);
#pragma unroll
            for (int j = 0; j < 4; ++j)
                bfr[j] = *(const bf16x8*)(Bs + (wn * 64 + j * 16 + lm) * 64 + sc);
#pragma unroll
            for (int i = 0; i < 4; ++i)
#pragma unroll
                for (int j = 0; j < 4; ++j)
                    acc[i][j] = __builtin_amdgcn_mfma_f32_16x16x32_bf16(af[i], bfr[j], acc[i][j], 0, 0, 0);
        }
        __syncthreads();
    }

    const int row0 = bm * 128 + wm * 64 + ((l >> 4) * 4);
    const int col0 = bn * 128 + wn * 64 + lm;
#pragma unroll
    for (int i = 0; i < 4; ++i)
#pragma unroll
        for (int j = 0; j < 4; ++j)
#pragma unroll
            for (int r = 0; r < 4; ++r)
                unsafeAtomicAdd(&C[(size_t)(row0 + i * 16 + r) * OUT_DIM + col0 + j * 16],
                                acc[i][j][r]);
}

// ---------------------------------------------------------------------------
extern "C" void kernel_launch(void* const* d_in, const int* in_sizes, int n_in,
                              void* d_out, int out_size, void* d_ws, size_t ws_size,
                              hipStream_t stream) {
    const float* x     = (const float*)d_in[0];   // (B, I)
    const float* sb    = (const float*)d_in[1];   // (O, I)
    const float* ss    = (const float*)d_in[2];   // (O, I)
    const float* coeff = (const float*)d_in[3];   // (2, O, I, G)
    float* out = (float*)d_out;                   // (B, O)

    uint8_t* A8 = (uint8_t*)d_ws;                          // 4096*16384 fp8 = 67.1 MB
    uint8_t* W8 = A8 + (size_t)BATCH * K8;                 // 1024*16384 fp8 = 16.8 MB
    __bf16*  Ab = (__bf16*)(W8 + (size_t)OUT_DIM * K8);    // 4096*1024 bf16 = 8.4 MB
    __bf16*  Wb = Ab + (size_t)BATCH * KB;                 // 1024*1024 bf16 = 2.1 MB

    hipLaunchKernelGGL(prep, dim3(2048 + 512), dim3(256), 0, stream,
                       x, sb, ss, coeff, A8, W8, Ab, Wb);
    hipMemsetAsync(out, 0, (size_t)BATCH * OUT_DIM * sizeof(float), stream);
    hipLaunchKernelGGL(gemm8, dim3(OUT_DIM / 128, BATCH / 128, SPLIT8), dim3(256), 0, stream,
                       A8, W8, out);
    hipLaunchKernelGGL(gemmb, dim3(OUT_DIM / 128, BATCH / 128, SPLITB), dim3(256), 0, stream,
                       Ab, Wb, out);
}

// Round 7
// 276.771 us; speedup vs baseline: 1.5759x; 1.0812x over previous
//
#include <hip/hip_runtime.h>
#include <hip/hip_bf16.h>
#include <stdint.h>

#define BATCH   4096
#define IN_DIM  1024
#define OUT_DIM 1024
#define GRID_G  8
#define K8      16384            // spline K: 16 planes (8 cos + 8 sin) * 1024
#define KB      1024             // base K (silu plane)
#define SPLIT8  4                // spline split-K: 32 iters of BK=128 bytes
#define WSCALE  256.0f           // spline weights scaled into e4m3 range

typedef __bf16 bf16x8 __attribute__((ext_vector_type(8)));
typedef float  f32x4  __attribute__((ext_vector_type(4)));
typedef int    i32x4  __attribute__((ext_vector_type(4)));
typedef int    i32x8  __attribute__((ext_vector_type(8)));

// pack 8 floats -> 8 fp8 e4m3 bytes (HW cvt), little-endian k-order
__device__ inline void store_fp8x8(void* p, const float v[8]) {
    int lo = 0, hi = 0;
    lo = __builtin_amdgcn_cvt_pk_fp8_f32(v[0], v[1], lo, false);
    lo = __builtin_amdgcn_cvt_pk_fp8_f32(v[2], v[3], lo, true);
    hi = __builtin_amdgcn_cvt_pk_fp8_f32(v[4], v[5], hi, false);
    hi = __builtin_amdgcn_cvt_pk_fp8_f32(v[6], v[7], hi, true);
    *(int2*)p = make_int2(lo, hi);
}

// ---------------------------------------------------------------------------
// Prep (merged): blocks [0,2048) build features; [2048,2560) fold weights.
// Spline planes (fp8): A8[b, p*1024+i], p=0..7 cos(g=p+1), p=8..15 sin(g=p-7).
// Base plane (bf16):   Ab[b,i] = silu(x);  Wb[o,i] = scale_base.
// W8[o, p*1024+i] = ss*coeff*WSCALE (fp8).
// ---------------------------------------------------------------------------
__global__ void prep(const float* __restrict__ x, const float* __restrict__ sb,
                     const float* __restrict__ ss, const float* __restrict__ coeff,
                     uint8_t* __restrict__ A8, uint8_t* __restrict__ W8,
                     __bf16* __restrict__ Ab, __bf16* __restrict__ Wb) {
    if (blockIdx.x < 2048) {
        int t  = blockIdx.x * blockDim.x + threadIdx.x;   // over BATCH*IN_DIM/8
        int b  = t >> 7;
        int i0 = (t & 127) * 8;
        const float4* xp = (const float4*)(x + (size_t)b * IN_DIM + i0);
        float4 x0 = xp[0], x1 = xp[1];
        float xv[8] = {x0.x, x0.y, x0.z, x0.w, x1.x, x1.y, x1.z, x1.w};

        float c1[8], s1[8], ck[8], sk[8];
        bf16x8 v;
#pragma unroll
        for (int j = 0; j < 8; ++j) {
            float sil = xv[j] / (1.f + __expf(-xv[j]));
            v[j] = (__bf16)sil;
            __sincosf(xv[j], &s1[j], &c1[j]);
            ck[j] = c1[j]; sk[j] = s1[j];
        }
        *(bf16x8*)(Ab + (size_t)b * IN_DIM + i0) = v;

        uint8_t* a8 = A8 + (size_t)b * K8 + i0;
#pragma unroll
        for (int g = 1; g <= GRID_G; ++g) {
            float vc[8], vs[8];
#pragma unroll
            for (int j = 0; j < 8; ++j) {
                vc[j] = ck[j];
                vs[j] = sk[j];
                float cn = ck[j] * c1[j] - sk[j] * s1[j];
                float sn = sk[j] * c1[j] + ck[j] * s1[j];
                ck[j] = cn; sk[j] = sn;
            }
            store_fp8x8(a8 + (size_t)(g - 1) * IN_DIM, vc);
            store_fp8x8(a8 + (size_t)(GRID_G + g - 1) * IN_DIM, vs);
        }
    } else {
        int t  = (blockIdx.x - 2048) * blockDim.x + threadIdx.x; // over OUT_DIM*IN_DIM/8
        int o  = t >> 7;
        int i0 = (t & 127) * 8;
        size_t oi = (size_t)o * IN_DIM + i0;

        float s[8];
        {
            const float4* sp = (const float4*)(ss + oi);
            float4 s0 = sp[0], s1 = sp[1];
            s[0]=s0.x; s[1]=s0.y; s[2]=s0.z; s[3]=s0.w;
            s[4]=s1.x; s[5]=s1.y; s[6]=s1.z; s[7]=s1.w;
        }
        {
            const float4* bp = (const float4*)(sb + oi);
            float4 b0 = bp[0], b1 = bp[1];
            float bv[8] = {b0.x, b0.y, b0.z, b0.w, b1.x, b1.y, b1.z, b1.w};
            bf16x8 v;
#pragma unroll
            for (int j = 0; j < 8; ++j) v[j] = (__bf16)bv[j];
            *(bf16x8*)(Wb + oi) = v;
        }
        uint8_t* w8 = W8 + (size_t)o * K8 + i0;
#pragma unroll
        for (int p = 0; p < 2; ++p) {
            const float* cp = coeff + ((size_t)p * OUT_DIM * IN_DIM + oi) * GRID_G;
            float c[8][8];                     // [j][g]
#pragma unroll
            for (int j = 0; j < 8; ++j) {
                const float4* cj = (const float4*)(cp + (size_t)j * GRID_G);
                float4 a0 = cj[0], a1 = cj[1];
                c[j][0]=a0.x; c[j][1]=a0.y; c[j][2]=a0.z; c[j][3]=a0.w;
                c[j][4]=a1.x; c[j][5]=a1.y; c[j][6]=a1.z; c[j][7]=a1.w;
            }
#pragma unroll
            for (int g = 0; g < GRID_G; ++g) {
                float v[8];
#pragma unroll
                for (int j = 0; j < 8; ++j) v[j] = s[j] * c[j][g] * WSCALE;
                store_fp8x8(w8 + (size_t)(p * GRID_G + g) * IN_DIM, v);
            }
        }
    }
}

// ---------------------------------------------------------------------------
// Unified GEMM. Grid (8, 32, 5):
//   z in [0,4): spline fp8, MX-scaled mfma 16x16x128 (unit scales), split-K x4,
//               BK=128 bytes, 32 iters/block.
//   z == 4:     base bf16, mfma 16x16x32, full K=1024, 16 iters of 64 elems.
// Both: 128x128 tile, 4 waves 2x2, 32 KB LDS (4 blocks/CU), XOR 16B-chunk
// swizzle (c ^ (row&7)) on staging global addr -> conflict-free b128 frag
// reads (each quarter-wave covers all 32 banks exactly 2x = minimum).
// Epilogue: HW f32 atomic add into zeroed C (proven under graph capture).
// ---------------------------------------------------------------------------
__global__ __launch_bounds__(256, 4) void gemm_all(const uint8_t* __restrict__ A8,
                                                   const uint8_t* __restrict__ W8,
                                                   const uint8_t* __restrict__ Ab,
                                                   const uint8_t* __restrict__ Wb,
                                                   float* __restrict__ C) {
    __shared__ __align__(16) uint8_t As[16384];
    __shared__ __align__(16) uint8_t Bs[16384];
    const int tid = threadIdx.x;
    const int w   = tid >> 6;
    const int l   = tid & 63;
    const int bn  = blockIdx.x;    // N/128 = 8
    const int bm  = blockIdx.y;    // M/128 = 32
    const int kz  = blockIdx.z;    // 0..3 spline chunks, 4 = base
    const int wm  = w & 1;
    const int wn  = w >> 1;

    f32x4 acc[4][4] = {};

    const int srow   = l >> 3;                  // 0..7
    const int schunk = ((l & 7) ^ srow) * 16;   // byte offset of swizzled 16B chunk
    const int lm = l & 15;
    const int q  = l >> 4;                      // 0..3
    float oscale;

    if (kz < SPLIT8) {
        // ---------------- spline fp8 path ----------------
        const uint8_t* Ag = A8 + (size_t)(bm * 128 + w * 32 + srow) * K8 + kz * (K8 / SPLIT8) + schunk;
        const uint8_t* Bg = W8 + (size_t)(bn * 128 + w * 32 + srow) * K8 + kz * (K8 / SPLIT8) + schunk;
        const int c0 = (q * 2) << 4, c1 = (q * 2 + 1) << 4;   // lane's two chunk offsets

        for (int ks = 0; ks < (K8 / SPLIT8) / 128; ++ks) {
#pragma unroll
            for (int j = 0; j < 4; ++j) {
                __builtin_amdgcn_global_load_lds(
                    (const uint32_t*)(Ag + (size_t)(j * 8) * K8),
                    (uint32_t*)(As + (w * 32 + j * 8) * 128), 16, 0, 0);
                __builtin_amdgcn_global_load_lds(
                    (const uint32_t*)(Bg + (size_t)(j * 8) * K8),
                    (uint32_t*)(Bs + (w * 32 + j * 8) * 128), 16, 0, 0);
            }
            Ag += 128; Bg += 128;
            __syncthreads();

            i32x8 bf[4];
#pragma unroll
            for (int j = 0; j < 4; ++j) {
                const int row = wn * 64 + j * 16 + lm;
                const int sw  = (row & 7) << 4;
                const uint8_t* rp = Bs + row * 128;
                i32x4 lo = *(const i32x4*)(rp + (c0 ^ sw));
                i32x4 hi = *(const i32x4*)(rp + (c1 ^ sw));
                bf[j] = __builtin_shufflevector(lo, hi, 0, 1, 2, 3, 4, 5, 6, 7);
            }
#pragma unroll
            for (int i = 0; i < 4; ++i) {
                const int row = wm * 64 + i * 16 + lm;
                const int sw  = (row & 7) << 4;
                const uint8_t* rp = As + row * 128;
                i32x4 lo = *(const i32x4*)(rp + (c0 ^ sw));
                i32x4 hi = *(const i32x4*)(rp + (c1 ^ sw));
                i32x8 af = __builtin_shufflevector(lo, hi, 0, 1, 2, 3, 4, 5, 6, 7);
#pragma unroll
                for (int j = 0; j < 4; ++j)
                    acc[i][j] = __builtin_amdgcn_mfma_scale_f32_16x16x128_f8f6f4(
                        af, bf[j], acc[i][j], 0, 0, 0, 0x7f7f7f7f, 0, 0x7f7f7f7f);
            }
            __syncthreads();
        }
        oscale = 1.0f / WSCALE;
    } else {
        // ---------------- base bf16 path (full K, no split) ----------------
        const uint8_t* Ag = Ab + (size_t)(bm * 128 + w * 32 + srow) * (KB * 2) + schunk;
        const uint8_t* Bg = Wb + (size_t)(bn * 128 + w * 32 + srow) * (KB * 2) + schunk;

        for (int ks = 0; ks < (KB * 2) / 128; ++ks) {
#pragma unroll
            for (int j = 0; j < 4; ++j) {
                __builtin_amdgcn_global_load_lds(
                    (const uint32_t*)(Ag + (size_t)(j * 8) * (KB * 2)),
                    (uint32_t*)(As + (w * 32 + j * 8) * 128), 16, 0, 0);
                __builtin_amdgcn_global_load_lds(
                    (const uint32_t*)(Bg + (size_t)(j * 8) * (KB * 2)),
                    (uint32_t*)(Bs + (w * 32 + j * 8) * 128), 16, 0, 0);
            }
            Ag += 128; Bg += 128;
            __syncthreads();

#pragma unroll
            for (int h = 0; h < 2; ++h) {
                bf16x8 af[4], bfr[4];
#pragma unroll
                for (int i = 0; i < 4; ++i) {
                    const int row = wm * 64 + i * 16 + lm;
                    af[i] = *(const bf16x8*)(As + row * 128 + ((((h * 4 + q) ^ (row & 7))) << 4));
                }
#pragma unroll
                for (int j = 0; j < 4; ++j) {
                    const int row = wn * 64 + j * 16 + lm;
                    bfr[j] = *(const bf16x8*)(Bs + row * 128 + ((((h * 4 + q) ^ (row & 7))) << 4));
                }
#pragma unroll
                for (int i = 0; i < 4; ++i)
#pragma unroll
                    for (int j = 0; j < 4; ++j)
                        acc[i][j] = __builtin_amdgcn_mfma_f32_16x16x32_bf16(af[i], bfr[j], acc[i][j], 0, 0, 0);
            }
            __syncthreads();
        }
        oscale = 1.0f;
    }

    // epilogue: C/D layout col = lane&15, row = (lane>>4)*4 + reg
    const int row0 = bm * 128 + wm * 64 + q * 4;
    const int col0 = bn * 128 + wn * 64 + lm;
#pragma unroll
    for (int i = 0; i < 4; ++i)
#pragma unroll
        for (int j = 0; j < 4; ++j)
#pragma unroll
            for (int r = 0; r < 4; ++r)
                unsafeAtomicAdd(&C[(size_t)(row0 + i * 16 + r) * OUT_DIM + col0 + j * 16],
                                acc[i][j][r] * oscale);
}

// ---------------------------------------------------------------------------
extern "C" void kernel_launch(void* const* d_in, const int* in_sizes, int n_in,
                              void* d_out, int out_size, void* d_ws, size_t ws_size,
                              hipStream_t stream) {
    const float* x     = (const float*)d_in[0];   // (B, I)
    const float* sb    = (const float*)d_in[1];   // (O, I)
    const float* ss    = (const float*)d_in[2];   // (O, I)
    const float* coeff = (const float*)d_in[3];   // (2, O, I, G)
    float* out = (float*)d_out;                   // (B, O)

    uint8_t* A8 = (uint8_t*)d_ws;                          // 4096*16384 fp8 = 67.1 MB
    uint8_t* W8 = A8 + (size_t)BATCH * K8;                 // 1024*16384 fp8 = 16.8 MB
    __bf16*  Ab = (__bf16*)(W8 + (size_t)OUT_DIM * K8);    // 4096*1024 bf16 = 8.4 MB
    __bf16*  Wb = Ab + (size_t)BATCH * KB;                 // 1024*1024 bf16 = 2.1 MB

    hipLaunchKernelGGL(prep, dim3(2048 + 512), dim3(256), 0, stream,
                       x, sb, ss, coeff, A8, W8, Ab, Wb);
    hipMemsetAsync(out, 0, (size_t)BATCH * OUT_DIM * sizeof(float), stream);
    hipLaunchKernelGGL(gemm_all, dim3(OUT_DIM / 128, BATCH / 128, SPLIT8 + 1), dim3(256), 0, stream,
                       A8, W8, (const uint8_t*)Ab, (const uint8_t*)Wb, out);
}